// Round 1
// 4199.690 us; speedup vs baseline: 1.2333x; 1.2333x over previous
//
#include <hip/hip_runtime.h>
#include <math.h>

// SimpleRNN: out[b,t,u] = h_t where h_t = tanh(x_t @ Wx + bias + h_{t-1} @ Wh)
// Phase 1: xp = x @ Wx + bias  (M=65536, K=256, N=512 fp32 GEMM) -> written to d_out
// Phase 2: rnn_scan2 -- 64 blocks x 1024 threads, 2 batches per block.
//   Main-loop role:  g = tid&127 -> u-cols [4g,4g+4), s = tid>>7 -> k-slice [64s,64s+64)
//   Reduce role:     b = tid>>9 (batch within pair), u = tid&511
//   Wh float4 loaded once per k serves 4 u's x 2 batches (8 FMAs per 16B from L2).
//   h broadcast from LDS as float4 (1 b128 feeds 16 FMAs).

#define BM 64
#define BN 64
#define BK 32

__global__ __launch_bounds__(256) void xp_gemm(
    const float* __restrict__ x,    // [65536, 256]
    const float* __restrict__ wx,   // [256, 512]
    const float* __restrict__ bias, // [512]
    float* __restrict__ out)        // [65536, 512]
{
    __shared__ float As[BK][BM + 4];
    __shared__ float Bs[BK][BN + 4];

    const int tid = threadIdx.x;
    const int m0 = blockIdx.y * BM;
    const int n0 = blockIdx.x * BN;
    const int tm = tid / 16;
    const int tn = tid % 16;

    float acc[4][4] = {};

    for (int k0 = 0; k0 < 256; k0 += BK) {
        {
            const int kk = tid % BK;
            const int r0 = tid / BK;
            #pragma unroll
            for (int rr = 0; rr < 8; ++rr) {
                const int m = r0 + rr * 8;
                As[kk][m] = x[(size_t)(m0 + m) * 256 + (k0 + kk)];
            }
        }
        {
            const int nn = tid % BN;
            const int r0 = tid / BN;
            #pragma unroll
            for (int rr = 0; rr < 8; ++rr) {
                const int k = r0 + rr * 4;
                Bs[k][nn] = wx[(size_t)(k0 + k) * 512 + (n0 + nn)];
            }
        }
        __syncthreads();

        #pragma unroll
        for (int kk = 0; kk < BK; ++kk) {
            const float4 a = *(const float4*)&As[kk][tm * 4];
            const float4 b = *(const float4*)&Bs[kk][tn * 4];
            const float av[4] = {a.x, a.y, a.z, a.w};
            const float bv[4] = {b.x, b.y, b.z, b.w};
            #pragma unroll
            for (int i = 0; i < 4; ++i) {
                #pragma unroll
                for (int j = 0; j < 4; ++j) {
                    acc[i][j] += av[i] * bv[j];
                }
            }
        }
        __syncthreads();
    }

    #pragma unroll
    for (int i = 0; i < 4; ++i) {
        const int m = m0 + tm * 4 + i;
        #pragma unroll
        for (int j = 0; j < 4; ++j) {
            const int n = n0 + tn * 4 + j;
            out[(size_t)m * 512 + n] = acc[i][j] + bias[n];
        }
    }
}

#define FMA4(A, W, H) { (A).x += (H)*(W).x; (A).y += (H)*(W).y; (A).z += (H)*(W).z; (A).w += (H)*(W).w; }

__global__ __launch_bounds__(1024, 4) void rnn_scan2(
    const float* __restrict__ wh,  // [512, 512] row-major (k, u)
    float* __restrict__ out)       // [128, 512, 512]: xp on input, h on output
{
    __shared__ float h_lds[2][512];     // h for batch pair
    __shared__ float red[8][2][512];    // k-split partials [s][b][u], 16 KB

    const int tid = threadIdx.x;
    const int g = tid & 127;    // u-group: covers u = 4g .. 4g+3
    const int s = tid >> 7;     // k-slice: k = 64s .. 64s+63
    const int b = tid >> 9;     // reduce role: batch within pair
    const int u = tid & 511;    // reduce role: output unit

    float* seqb = out + (size_t)(2 * blockIdx.x + b) * 512 * 512;

    h_lds[b][u] = 0.0f;
    __syncthreads();

    const float4* __restrict__ whv = (const float4*)wh;  // [512][128] of float4
    const int kbase = s * 64;

    for (int t = 0; t < 512; ++t) {
        // xp for this thread's output; issued early, consumed after the k-loop.
        const float xpv = seqb[(size_t)t * 512 + u];

        float4 a0 = make_float4(0.f, 0.f, 0.f, 0.f);  // batch 0, u=4g..4g+3
        float4 a1 = make_float4(0.f, 0.f, 0.f, 0.f);  // batch 1

        #pragma unroll 4
        for (int kk = 0; kk < 64; kk += 4) {
            const int k = kbase + kk;
            const float4 h0 = *(const float4*)&h_lds[0][k];  // broadcast across wave
            const float4 h1 = *(const float4*)&h_lds[1][k];
            const float4 w0 = whv[(k + 0) * 128 + g];  // coalesced 1KB/wave
            const float4 w1 = whv[(k + 1) * 128 + g];
            const float4 w2 = whv[(k + 2) * 128 + g];
            const float4 w3 = whv[(k + 3) * 128 + g];

            FMA4(a0, w0, h0.x) FMA4(a0, w1, h0.y) FMA4(a0, w2, h0.z) FMA4(a0, w3, h0.w)
            FMA4(a1, w0, h1.x) FMA4(a1, w1, h1.y) FMA4(a1, w2, h1.z) FMA4(a1, w3, h1.w)
        }

        *(float4*)&red[s][0][4 * g] = a0;
        *(float4*)&red[s][1][4 * g] = a1;
        __syncthreads();   // partials complete; everyone done reading old h

        float r = xpv;
        #pragma unroll
        for (int ss = 0; ss < 8; ++ss) r += red[ss][b][u];  // consecutive lanes -> consecutive banks
        const float hn = tanhf(r);
        h_lds[b][u] = hn;                      // disjoint from red; safe pre-barrier
        seqb[(size_t)t * 512 + u] = hn;        // coalesced store
        __syncthreads();   // new h visible before next step's k-loop
    }
}

extern "C" void kernel_launch(void* const* d_in, const int* in_sizes, int n_in,
                              void* d_out, int out_size, void* d_ws, size_t ws_size,
                              hipStream_t stream) {
    const float* x    = (const float*)d_in[0];  // [128,512,256]
    const float* wx   = (const float*)d_in[1];  // [256,512]
    const float* wh   = (const float*)d_in[2];  // [512,512]
    const float* bias = (const float*)d_in[3];  // [512]
    float* out = (float*)d_out;                 // [128,512,512]

    dim3 g1(512 / BN, 65536 / BM);
    xp_gemm<<<g1, 256, 0, stream>>>(x, wx, bias, out);
    rnn_scan2<<<64, 1024, 0, stream>>>(wh, out);
}

// Round 2
// 3273.971 us; speedup vs baseline: 1.5820x; 1.2828x over previous
//
#include <hip/hip_runtime.h>
#include <math.h>

// SimpleRNN: out[b,t,u] = h_t where h_t = tanh(x_t @ Wx + bias + h_{t-1} @ Wh)
// Phase 1: xp = x @ Wx + bias  (M=65536, K=256, N=512 fp32 GEMM) -> written to d_out
// Phase 2: rnn_scan3 -- persistent-style decomposition:
//   grid = 256 blocks = 4 u-slices x 64 batch-groups (2 batches each), 1024 thr.
//   Each block holds Wh[:, 128-col slice] in REGISTERS (64 VGPR/thread) for the
//   whole scan -> zero per-step Wh traffic (was 1 MB/step/CU = the R1 wall).
//   Per step: h_prev for the 2 batches is read device-coherently from out[:,t-1,:]
//   (written by the 4 sibling blocks), staged in LDS, FMA'd against reg-Wh,
//   k-slice partials reduced via LDS, tanh+store, then a 4-block flag sync.
//   84 KB static LDS forces 1 block/CU -> all 256 blocks co-resident -> no deadlock.

#define BM 64
#define BN 64
#define BK 32

__global__ __launch_bounds__(256) void xp_gemm(
    const float* __restrict__ x,    // [65536, 256]
    const float* __restrict__ wx,   // [256, 512]
    const float* __restrict__ bias, // [512]
    float* __restrict__ out)        // [65536, 512]
{
    __shared__ float As[BK][BM + 4];
    __shared__ float Bs[BK][BN + 4];

    const int tid = threadIdx.x;
    const int m0 = blockIdx.y * BM;
    const int n0 = blockIdx.x * BN;
    const int tm = tid / 16;
    const int tn = tid % 16;

    float acc[4][4] = {};

    for (int k0 = 0; k0 < 256; k0 += BK) {
        {
            const int kk = tid % BK;
            const int r0 = tid / BK;
            #pragma unroll
            for (int rr = 0; rr < 8; ++rr) {
                const int m = r0 + rr * 8;
                As[kk][m] = x[(size_t)(m0 + m) * 256 + (k0 + kk)];
            }
        }
        {
            const int nn = tid % BN;
            const int r0 = tid / BN;
            #pragma unroll
            for (int rr = 0; rr < 8; ++rr) {
                const int k = r0 + rr * 4;
                Bs[k][nn] = wx[(size_t)(k0 + k) * 512 + (n0 + nn)];
            }
        }
        __syncthreads();

        #pragma unroll
        for (int kk = 0; kk < BK; ++kk) {
            const float4 a = *(const float4*)&As[kk][tm * 4];
            const float4 b = *(const float4*)&Bs[kk][tn * 4];
            const float av[4] = {a.x, a.y, a.z, a.w};
            const float bv[4] = {b.x, b.y, b.z, b.w};
            #pragma unroll
            for (int i = 0; i < 4; ++i) {
                #pragma unroll
                for (int j = 0; j < 4; ++j) {
                    acc[i][j] += av[i] * bv[j];
                }
            }
        }
        __syncthreads();
    }

    #pragma unroll
    for (int i = 0; i < 4; ++i) {
        const int m = m0 + tm * 4 + i;
        #pragma unroll
        for (int j = 0; j < 4; ++j) {
            const int n = n0 + tn * 4 + j;
            out[(size_t)m * 512 + n] = acc[i][j] + bias[n];
        }
    }
}

#define FMA4(A, W, H) { (A).x += (H)*(W).x; (A).y += (H)*(W).y; (A).z += (H)*(W).z; (A).w += (H)*(W).w; }

__global__ __launch_bounds__(1024) void rnn_scan3(
    const float* __restrict__ wh,   // [512, 512] row-major (k, u)
    float* __restrict__ out,        // [128, 512, 512]: xp on input, h on output
    int* __restrict__ flags)        // [64 groups][512 steps]
{
    // 84 KB static LDS: h_lds [2][512] (4KB) + red [32][2][128] (32KB) + pad.
    // >80KB guarantees 1 block/CU -> 256 blocks co-resident on 256 CUs.
    __shared__ float smem[21504];
    float* h_lds = smem;          // [2][512]
    float* red   = smem + 1024;   // [s=32][b=2][u=128]

    const int tid = threadIdx.x;
    const int us  = blockIdx.x & 3;    // u-slice 0..3
    const int bg  = blockIdx.x >> 2;   // batch-group 0..63
    const int u0  = us * 128;
    const int g   = tid & 31;          // u-group: u = u0 + 4g .. u0+4g+3
    const int s   = tid >> 5;          // k-slice: k = 16s .. 16s+15
    const int kbase = s * 16;

    // Wh block -> registers: w[i] = wh[kbase+i][u0+4g .. +3]   (64 VGPRs)
    float4 w[16];
    #pragma unroll
    for (int i = 0; i < 16; ++i)
        w[i] = *(const float4*)&wh[(size_t)(kbase + i) * 512 + (u0 + 4 * g)];

    float* out0 = out + (size_t)(bg * 2 + 0) * (512 * 512);
    float* out1 = out + (size_t)(bg * 2 + 1) * (512 * 512);

    const int ru = tid & 127;   // reduce role: u offset in slice
    const int rb = tid >> 7;    // reduce role: batch (only tid<256 active)
    int* myflag = flags + bg * 512;

    for (int t = 0; t < 512; ++t) {
        // xp prefetch (own u-slice of out[:,t,:]; nobody else ever writes it)
        float xpv = 0.f;
        if (tid < 256) {
            const float* op = (rb == 0) ? out0 : out1;
            xpv = op[(size_t)t * 512 + u0 + ru];
        }

        if (t == 0) {
            h_lds[tid] = 0.f;   // tid<1024 covers [2][512]
        } else {
            if (tid == 0) {
                int v, cnt = 0;
                do {
                    v = __hip_atomic_load(&myflag[t - 1], __ATOMIC_RELAXED, __HIP_MEMORY_SCOPE_AGENT);
                    if (v < 4) __builtin_amdgcn_s_sleep(2);
                } while (v < 4 && ++cnt < (1 << 22));
                (void)__hip_atomic_load(&myflag[t - 1], __ATOMIC_ACQUIRE, __HIP_MEMORY_SCOPE_AGENT);
            }
            __syncthreads();   // flag observed for whole block
            // stage h_prev = out[b][t-1][:] via device-coherent loads (cross-XCD safe)
            const int hb = tid >> 9;    // 0/1
            const int hk = tid & 511;
            const float* src = ((hb == 0) ? out0 : out1) + (size_t)(t - 1) * 512 + hk;
            h_lds[hb * 512 + hk] = __hip_atomic_load(src, __ATOMIC_RELAXED, __HIP_MEMORY_SCOPE_AGENT);
        }
        __syncthreads();   // h_lds ready

        float4 a0 = make_float4(0.f, 0.f, 0.f, 0.f);
        float4 a1 = make_float4(0.f, 0.f, 0.f, 0.f);
        #pragma unroll
        for (int i = 0; i < 4; ++i) {
            const float4 h0 = *(const float4*)&h_lds[0 * 512 + kbase + 4 * i];  // broadcast
            const float4 h1 = *(const float4*)&h_lds[1 * 512 + kbase + 4 * i];
            FMA4(a0, w[4*i+0], h0.x) FMA4(a0, w[4*i+1], h0.y) FMA4(a0, w[4*i+2], h0.z) FMA4(a0, w[4*i+3], h0.w)
            FMA4(a1, w[4*i+0], h1.x) FMA4(a1, w[4*i+1], h1.y) FMA4(a1, w[4*i+2], h1.z) FMA4(a1, w[4*i+3], h1.w)
        }
        *(float4*)&red[(s * 2 + 0) * 128 + 4 * g] = a0;
        *(float4*)&red[(s * 2 + 1) * 128 + 4 * g] = a1;
        __syncthreads();   // partials complete; everyone done reading h_lds

        if (tid < 256) {
            float r = xpv;
            #pragma unroll
            for (int ss = 0; ss < 32; ++ss) r += red[(ss * 2 + rb) * 128 + ru];
            const float hn = tanhf(r);
            float* op = (rb == 0) ? out0 : out1;
            __hip_atomic_store(&op[(size_t)t * 512 + u0 + ru], hn,
                               __ATOMIC_RELAXED, __HIP_MEMORY_SCOPE_AGENT);
        }
        __syncthreads();   // storing waves drained (vmcnt) before signaling
        if (tid == 0) {
            __hip_atomic_fetch_add(&myflag[t], 1, __ATOMIC_RELEASE, __HIP_MEMORY_SCOPE_AGENT);
        }
        // h_lds/red reuse next iter is safe: rewritten only after the next
        // post-stage __syncthreads, which all threads (incl. reducers) must pass.
    }
}

// ---- fallback (round-1 kernel) if workspace is too small for flags ----
__global__ __launch_bounds__(1024, 4) void rnn_scan2(
    const float* __restrict__ wh, float* __restrict__ out)
{
    __shared__ float h_lds[2][512];
    __shared__ float red[8][2][512];

    const int tid = threadIdx.x;
    const int g = tid & 127;
    const int s = tid >> 7;
    const int b = tid >> 9;
    const int u = tid & 511;

    float* seqb = out + (size_t)(2 * blockIdx.x + b) * 512 * 512;
    h_lds[b][u] = 0.0f;
    __syncthreads();

    const float4* __restrict__ whv = (const float4*)wh;
    const int kbase = s * 64;

    for (int t = 0; t < 512; ++t) {
        const float xpv = seqb[(size_t)t * 512 + u];
        float4 a0 = make_float4(0.f, 0.f, 0.f, 0.f);
        float4 a1 = make_float4(0.f, 0.f, 0.f, 0.f);
        #pragma unroll 4
        for (int kk = 0; kk < 64; kk += 4) {
            const int k = kbase + kk;
            const float4 h0 = *(const float4*)&h_lds[0][k];
            const float4 h1 = *(const float4*)&h_lds[1][k];
            const float4 w0 = whv[(k + 0) * 128 + g];
            const float4 w1 = whv[(k + 1) * 128 + g];
            const float4 w2 = whv[(k + 2) * 128 + g];
            const float4 w3 = whv[(k + 3) * 128 + g];
            FMA4(a0, w0, h0.x) FMA4(a0, w1, h0.y) FMA4(a0, w2, h0.z) FMA4(a0, w3, h0.w)
            FMA4(a1, w0, h1.x) FMA4(a1, w1, h1.y) FMA4(a1, w2, h1.z) FMA4(a1, w3, h1.w)
        }
        *(float4*)&red[s][0][4 * g] = a0;
        *(float4*)&red[s][1][4 * g] = a1;
        __syncthreads();
        float r = xpv;
        #pragma unroll
        for (int ss = 0; ss < 8; ++ss) r += red[ss][b][u];
        const float hn = tanhf(r);
        h_lds[b][u] = hn;
        seqb[(size_t)t * 512 + u] = hn;
        __syncthreads();
    }
}

extern "C" void kernel_launch(void* const* d_in, const int* in_sizes, int n_in,
                              void* d_out, int out_size, void* d_ws, size_t ws_size,
                              hipStream_t stream) {
    const float* x    = (const float*)d_in[0];  // [128,512,256]
    const float* wx   = (const float*)d_in[1];  // [256,512]
    const float* wh   = (const float*)d_in[2];  // [512,512]
    const float* bias = (const float*)d_in[3];  // [512]
    float* out = (float*)d_out;                 // [128,512,512]

    dim3 g1(512 / BN, 65536 / BM);
    xp_gemm<<<g1, 256, 0, stream>>>(x, wx, bias, out);

    const size_t flag_bytes = 64 * 512 * sizeof(int);
    if (ws_size >= flag_bytes && d_ws != nullptr) {
        hipMemsetAsync(d_ws, 0, flag_bytes, stream);
        rnn_scan3<<<256, 1024, 0, stream>>>(wh, out, (int*)d_ws);
    } else {
        rnn_scan2<<<64, 1024, 0, stream>>>(wh, out);
    }
}

// Round 3
// 1224.918 us; speedup vs baseline: 4.2284x; 2.6728x over previous
//
#include <hip/hip_runtime.h>
#include <math.h>

// SimpleRNN: out[b,t,u] = h_t where h_t = tanh(x_t @ Wx + bias + h_{t-1} @ Wh)
// Phase 1: xp = x @ Wx + bias  -> workspace (d_ws)
// Phase 0: out prefilled with sentinel bytes 0xFF (-NaN; tanh can never produce it)
// Phase 2: rnn_scan4 -- 256 blocks = 4 u-slices x 64 batch-groups (2 batches), 1024 thr.
//   Wh[:,128-slice] pinned in 16 NAMED float4 registers per thread (64 VGPRs).
//   h exchange: producers publish h_t to out[] with relaxed agent atomic stores
//   (data IS the flag); consumers poll the values until != sentinel. No fences,
//   no flag round trip, no L2 invalidate/writeback churn.

#define BM 64
#define BN 64
#define BK 32
#define SENT 0xFFFFFFFFu

__global__ __launch_bounds__(256) void xp_gemm(
    const float* __restrict__ x,    // [65536, 256]
    const float* __restrict__ wx,   // [256, 512]
    const float* __restrict__ bias, // [512]
    float* __restrict__ xp)         // [65536, 512] (workspace)
{
    __shared__ float As[BK][BM + 4];
    __shared__ float Bs[BK][BN + 4];

    const int tid = threadIdx.x;
    const int m0 = blockIdx.y * BM;
    const int n0 = blockIdx.x * BN;
    const int tm = tid / 16;
    const int tn = tid % 16;

    float acc[4][4] = {};

    for (int k0 = 0; k0 < 256; k0 += BK) {
        {
            const int kk = tid % BK;
            const int r0 = tid / BK;
            #pragma unroll
            for (int rr = 0; rr < 8; ++rr) {
                const int m = r0 + rr * 8;
                As[kk][m] = x[(size_t)(m0 + m) * 256 + (k0 + kk)];
            }
        }
        {
            const int nn = tid % BN;
            const int r0 = tid / BN;
            #pragma unroll
            for (int rr = 0; rr < 8; ++rr) {
                const int k = r0 + rr * 4;
                Bs[k][nn] = wx[(size_t)(k0 + k) * 512 + (n0 + nn)];
            }
        }
        __syncthreads();

        #pragma unroll
        for (int kk = 0; kk < BK; ++kk) {
            const float4 a = *(const float4*)&As[kk][tm * 4];
            const float4 b = *(const float4*)&Bs[kk][tn * 4];
            const float av[4] = {a.x, a.y, a.z, a.w};
            const float bv[4] = {b.x, b.y, b.z, b.w};
            #pragma unroll
            for (int i = 0; i < 4; ++i)
                #pragma unroll
                for (int j = 0; j < 4; ++j)
                    acc[i][j] += av[i] * bv[j];
        }
        __syncthreads();
    }

    #pragma unroll
    for (int i = 0; i < 4; ++i) {
        const int m = m0 + tm * 4 + i;
        #pragma unroll
        for (int j = 0; j < 4; ++j) {
            const int n = n0 + tn * 4 + j;
            xp[(size_t)m * 512 + n] = acc[i][j] + bias[n];
        }
    }
}

#define FMA4(A, W, H) { (A).x += (H)*(W).x; (A).y += (H)*(W).y; (A).z += (H)*(W).z; (A).w += (H)*(W).w; }

__global__ __launch_bounds__(1024) void rnn_scan4(
    const float* __restrict__ wh,   // [512, 512] row-major (k, u)
    const float* __restrict__ xp,   // [128, 512, 512] (workspace)
    float* __restrict__ out)        // [128, 512, 512] sentinel-prefilled; h written here
{
    __shared__ float h_lds[2][512];        // 4 KB
    __shared__ float red[32][2][128];      // 32 KB

    const int tid = threadIdx.x;
    const int us  = blockIdx.x & 3;    // u-slice 0..3
    const int bg  = blockIdx.x >> 2;   // batch-group 0..63
    const int u0  = us * 128;
    const int g   = tid & 31;          // u-quad: u = u0+4g .. u0+4g+3
    const int s   = tid >> 5;          // k-slice: k = 16s .. 16s+15
    const int kbase = s * 16;
    const size_t seq = 512 * 512;

    // ---- Wh slice in 16 NAMED float4 regs (prevents demotion/remat) ----
    const float* wr = &wh[(size_t)kbase * 512 + (u0 + 4 * g)];
    const float4 w0  = *(const float4*)(wr + 0  * 512);
    const float4 w1  = *(const float4*)(wr + 1  * 512);
    const float4 w2  = *(const float4*)(wr + 2  * 512);
    const float4 w3  = *(const float4*)(wr + 3  * 512);
    const float4 w4  = *(const float4*)(wr + 4  * 512);
    const float4 w5  = *(const float4*)(wr + 5  * 512);
    const float4 w6  = *(const float4*)(wr + 6  * 512);
    const float4 w7  = *(const float4*)(wr + 7  * 512);
    const float4 w8  = *(const float4*)(wr + 8  * 512);
    const float4 w9  = *(const float4*)(wr + 9  * 512);
    const float4 w10 = *(const float4*)(wr + 10 * 512);
    const float4 w11 = *(const float4*)(wr + 11 * 512);
    const float4 w12 = *(const float4*)(wr + 12 * 512);
    const float4 w13 = *(const float4*)(wr + 13 * 512);
    const float4 w14 = *(const float4*)(wr + 14 * 512);
    const float4 w15 = *(const float4*)(wr + 15 * 512);

    // reduce role (tid < 256): output unit u0+ru of batch rb
    const int ru = tid & 127;
    const int rb = (tid >> 7) & 1;
    const float* xpp = xp + (size_t)(bg * 2 + rb) * seq + u0 + ru;   // + t*512
    float*       hop = out + (size_t)(bg * 2 + rb) * seq + u0 + ru;  // + t*512

    // stage role (tid < 768): poll remote h element (sb, shk)
    const int sb   = (tid >= 384) ? 1 : 0;
    const int srem = tid - sb * 384;               // 0..383
    const int shk  = (srem < u0) ? srem : srem + 128;  // skip own slice
    const float* pollp = out + (size_t)(bg * 2 + sb) * seq + shk;    // + (t-1)*512

    for (int t = 0; t < 512; ++t) {
        float xpv = 0.0f;
        if (tid < 256) xpv = xpp[(size_t)t * 512];   // issued early, used post-reduce

        if (t == 0) {
            ((float*)h_lds)[tid] = 0.0f;             // 1024 threads cover [2][512]
        } else if (tid < 768) {
            const float* p = pollp + (size_t)(t - 1) * 512;
            float v;
            int cnt = 0;
            do {
                v = __hip_atomic_load(p, __ATOMIC_RELAXED, __HIP_MEMORY_SCOPE_AGENT);
                if (__float_as_uint(v) != SENT) break;
                __builtin_amdgcn_s_sleep(1);
            } while (++cnt < (1 << 20));
            h_lds[sb][shk] = v;
        }
        __syncthreads();   // full h_{t-1} staged

        float4 a0 = make_float4(0.f, 0.f, 0.f, 0.f);
        float4 a1 = make_float4(0.f, 0.f, 0.f, 0.f);
        const float* hb0 = &h_lds[0][kbase];
        const float* hb1 = &h_lds[1][kbase];
        #define STEP4(W0, W1, W2, W3, OFF) { \
            const float4 h0 = *(const float4*)(hb0 + (OFF)); \
            const float4 h1 = *(const float4*)(hb1 + (OFF)); \
            FMA4(a0, W0, h0.x) FMA4(a0, W1, h0.y) FMA4(a0, W2, h0.z) FMA4(a0, W3, h0.w) \
            FMA4(a1, W0, h1.x) FMA4(a1, W1, h1.y) FMA4(a1, W2, h1.z) FMA4(a1, W3, h1.w) }
        STEP4(w0,  w1,  w2,  w3,  0)
        STEP4(w4,  w5,  w6,  w7,  4)
        STEP4(w8,  w9,  w10, w11, 8)
        STEP4(w12, w13, w14, w15, 12)
        #undef STEP4

        *(float4*)&red[s][0][4 * g] = a0;
        *(float4*)&red[s][1][4 * g] = a1;
        __syncthreads();   // partials ready; all h_lds reads done

        if (tid < 256) {
            float r = xpv;
            #pragma unroll
            for (int ss = 0; ss < 32; ++ss) r += red[ss][rb][ru];
            const float hn = tanhf(r);
            h_lds[rb][u0 + ru] = hn;   // own slice for next step (no round trip)
            __hip_atomic_store(hop + (size_t)t * 512, hn,
                               __ATOMIC_RELAXED, __HIP_MEMORY_SCOPE_AGENT);
        }
        __syncthreads();   // own-slice h_lds visible; red safe to overwrite
    }
}

// ---- fallback: R2 flag-sync version (ws >= 128 KB but < 128 MB) ----
__global__ __launch_bounds__(1024) void rnn_scan3(
    const float* __restrict__ wh, float* __restrict__ out, int* __restrict__ flags)
{
    __shared__ float smem[21504];
    float* h_lds = smem;
    float* red   = smem + 1024;

    const int tid = threadIdx.x;
    const int us  = blockIdx.x & 3;
    const int bg  = blockIdx.x >> 2;
    const int u0  = us * 128;
    const int g   = tid & 31;
    const int s   = tid >> 5;
    const int kbase = s * 16;

    float4 w[16];
    #pragma unroll
    for (int i = 0; i < 16; ++i)
        w[i] = *(const float4*)&wh[(size_t)(kbase + i) * 512 + (u0 + 4 * g)];

    float* out0 = out + (size_t)(bg * 2 + 0) * (512 * 512);
    float* out1 = out + (size_t)(bg * 2 + 1) * (512 * 512);
    const int ru = tid & 127;
    const int rb = tid >> 7;
    int* myflag = flags + bg * 512;

    for (int t = 0; t < 512; ++t) {
        float xpv = 0.f;
        if (tid < 256) {
            const float* op = (rb == 0) ? out0 : out1;
            xpv = op[(size_t)t * 512 + u0 + ru];
        }
        if (t == 0) {
            h_lds[tid] = 0.f;
        } else {
            if (tid == 0) {
                int v, cnt = 0;
                do {
                    v = __hip_atomic_load(&myflag[t - 1], __ATOMIC_RELAXED, __HIP_MEMORY_SCOPE_AGENT);
                    if (v < 4) __builtin_amdgcn_s_sleep(2);
                } while (v < 4 && ++cnt < (1 << 22));
                (void)__hip_atomic_load(&myflag[t - 1], __ATOMIC_ACQUIRE, __HIP_MEMORY_SCOPE_AGENT);
            }
            __syncthreads();
            const int hb = tid >> 9;
            const int hk = tid & 511;
            const float* src = ((hb == 0) ? out0 : out1) + (size_t)(t - 1) * 512 + hk;
            h_lds[hb * 512 + hk] = __hip_atomic_load(src, __ATOMIC_RELAXED, __HIP_MEMORY_SCOPE_AGENT);
        }
        __syncthreads();

        float4 a0 = make_float4(0.f, 0.f, 0.f, 0.f);
        float4 a1 = make_float4(0.f, 0.f, 0.f, 0.f);
        #pragma unroll
        for (int i = 0; i < 4; ++i) {
            const float4 h0 = *(const float4*)&h_lds[0 * 512 + kbase + 4 * i];
            const float4 h1 = *(const float4*)&h_lds[1 * 512 + kbase + 4 * i];
            FMA4(a0, w[4*i+0], h0.x) FMA4(a0, w[4*i+1], h0.y) FMA4(a0, w[4*i+2], h0.z) FMA4(a0, w[4*i+3], h0.w)
            FMA4(a1, w[4*i+0], h1.x) FMA4(a1, w[4*i+1], h1.y) FMA4(a1, w[4*i+2], h1.z) FMA4(a1, w[4*i+3], h1.w)
        }
        *(float4*)&red[(s * 2 + 0) * 128 + 4 * g] = a0;
        *(float4*)&red[(s * 2 + 1) * 128 + 4 * g] = a1;
        __syncthreads();

        if (tid < 256) {
            float r = xpv;
            #pragma unroll
            for (int ss = 0; ss < 32; ++ss) r += red[(ss * 2 + rb) * 128 + ru];
            const float hn = tanhf(r);
            float* op = (rb == 0) ? out0 : out1;
            __hip_atomic_store(&op[(size_t)t * 512 + u0 + ru], hn,
                               __ATOMIC_RELAXED, __HIP_MEMORY_SCOPE_AGENT);
        }
        __syncthreads();
        if (tid == 0)
            __hip_atomic_fetch_add(&myflag[t], 1, __ATOMIC_RELEASE, __HIP_MEMORY_SCOPE_AGENT);
    }
}

// ---- fallback: R1 single-block-per-pair version (no usable ws) ----
__global__ __launch_bounds__(1024, 4) void rnn_scan2(
    const float* __restrict__ wh, float* __restrict__ out)
{
    __shared__ float h_lds[2][512];
    __shared__ float red[8][2][512];

    const int tid = threadIdx.x;
    const int g = tid & 127;
    const int s = tid >> 7;
    const int b = tid >> 9;
    const int u = tid & 511;

    float* seqb = out + (size_t)(2 * blockIdx.x + b) * 512 * 512;
    h_lds[b][u] = 0.0f;
    __syncthreads();

    const float4* __restrict__ whv = (const float4*)wh;
    const int kbase = s * 64;

    for (int t = 0; t < 512; ++t) {
        const float xpv = seqb[(size_t)t * 512 + u];
        float4 a0 = make_float4(0.f, 0.f, 0.f, 0.f);
        float4 a1 = make_float4(0.f, 0.f, 0.f, 0.f);
        #pragma unroll 4
        for (int kk = 0; kk < 64; kk += 4) {
            const int k = kbase + kk;
            const float4 h0 = *(const float4*)&h_lds[0][k];
            const float4 h1 = *(const float4*)&h_lds[1][k];
            const float4 v0 = whv[(k + 0) * 128 + g];
            const float4 v1 = whv[(k + 1) * 128 + g];
            const float4 v2 = whv[(k + 2) * 128 + g];
            const float4 v3 = whv[(k + 3) * 128 + g];
            FMA4(a0, v0, h0.x) FMA4(a0, v1, h0.y) FMA4(a0, v2, h0.z) FMA4(a0, v3, h0.w)
            FMA4(a1, v0, h1.x) FMA4(a1, v1, h1.y) FMA4(a1, v2, h1.z) FMA4(a1, v3, h1.w)
        }
        *(float4*)&red[s][0][4 * g] = a0;
        *(float4*)&red[s][1][4 * g] = a1;
        __syncthreads();
        float r = xpv;
        #pragma unroll
        for (int ss = 0; ss < 8; ++ss) r += red[ss][b][u];
        const float hn = tanhf(r);
        h_lds[b][u] = hn;
        seqb[(size_t)t * 512 + u] = hn;
        __syncthreads();
    }
}

extern "C" void kernel_launch(void* const* d_in, const int* in_sizes, int n_in,
                              void* d_out, int out_size, void* d_ws, size_t ws_size,
                              hipStream_t stream) {
    const float* x    = (const float*)d_in[0];  // [128,512,256]
    const float* wx   = (const float*)d_in[1];  // [256,512]
    const float* wh   = (const float*)d_in[2];  // [512,512]
    const float* bias = (const float*)d_in[3];  // [512]
    float* out = (float*)d_out;                 // [128,512,512]

    dim3 g1(512 / BN, 65536 / BM);
    const size_t xp_bytes = (size_t)128 * 512 * 512 * sizeof(float);
    const size_t flag_bytes = 64 * 512 * sizeof(int);

    if (d_ws != nullptr && ws_size >= xp_bytes) {
        // Primary path: xp in workspace, out sentinel-filled, data-as-flag scan.
        hipMemsetAsync(d_out, 0xFF, xp_bytes, stream);
        xp_gemm<<<g1, 256, 0, stream>>>(x, wx, bias, (float*)d_ws);
        rnn_scan4<<<256, 1024, 0, stream>>>(wh, (const float*)d_ws, out);
    } else if (d_ws != nullptr && ws_size >= flag_bytes) {
        hipMemsetAsync(d_ws, 0, flag_bytes, stream);
        xp_gemm<<<g1, 256, 0, stream>>>(x, wx, bias, out);
        rnn_scan3<<<256, 1024, 0, stream>>>(wh, out, (int*)d_ws);
    } else {
        xp_gemm<<<g1, 256, 0, stream>>>(x, wx, bias, out);
        rnn_scan2<<<64, 1024, 0, stream>>>(wh, out);
    }
}